// Round 12
// baseline (625.786 us; speedup 1.0000x reference)
//
#include <hip/hip_runtime.h>
#include <hip/hip_bf16.h>

// AutoInt+MLP fused forward, MI355X gfx950.  Round 12:
//  - Merge experiment (r11) REVERTED: heterogeneous block roles shared worst-case
//    VGPR (108) and thrashed L2 (FETCH +60MB) -> 490us regression.
//  - attn: round-10 verbatim (arena, 52224B LDS, 3 blocks/CU, 276us proven).
//  - dnn : round-6 M=64 structure (256 blocks, packed B-loads, 8-chunk phase 2)
//          WITHOUT the poison 2-arg __launch_bounds__ — testing whether r6's
//          1.3GB spill was bound-induced (allocator capped at 100 VGPR w/ 128
//          live accs). Halves W1 L2 traffic, 2x MFMA per B-load.
//  HARD RULE: never use 2-arg __launch_bounds__ (r5/r8/r9 corrupt, r6 spill).

#define NF     39
#define EMB    64
#define NLAYER 3
#define VOCAB  1000
#define FLAT   2496
#define H1     512
#define H2     256

typedef __attribute__((ext_vector_type(8))) short  short8;
typedef __attribute__((ext_vector_type(4))) float  floatx4;

__device__ __forceinline__ short8 ld8s(const unsigned short* p) {
    return *(const short8*)p;
}
__device__ __forceinline__ float b2f(unsigned short h) {
    union { unsigned u; float f; } x; x.u = ((unsigned)h) << 16; return x.f;
}
__device__ __forceinline__ unsigned short f2b(float f) {
    union { float f; unsigned u; } x; x.f = f;
    unsigned u = x.u;
    return (unsigned short)((u + 0x7fffu + ((u >> 16) & 1u)) >> 16);
}
// 2 floats -> packed bf16x2 in ONE VALU op (gfx950 hw cvt, RNE)
__device__ __forceinline__ unsigned cvt_pk(float a, float b) {
#if defined(__gfx950__)
    unsigned r;
    asm("v_cvt_pk_bf16_f32 %0, %1, %2" : "=v"(r) : "v"(a), "v"(b));
    return r;
#else
    return (unsigned)f2b(a) | ((unsigned)f2b(b) << 16);
#endif
}

// ------- prep: attention weights f32 [L][64(k)][64(o)] -> bf16 [L][o][k] --------------
__global__ void attw_t(const float* __restrict__ WQ, const float* __restrict__ WK,
                       const float* __restrict__ WV, const float* __restrict__ WR,
                       unsigned short* __restrict__ wqt, unsigned short* __restrict__ wkt,
                       unsigned short* __restrict__ wvt, unsigned short* __restrict__ wrt)
{
    int idx = blockIdx.x * 256 + threadIdx.x;       // 4*3*4096 = 49152
    if (idx >= 4 * 3 * 4096) return;
    int mat = idx / 12288;
    int rem = idx % 12288;
    int l   = rem / 4096;
    int ok  = rem % 4096;
    int o = ok >> 6, k = ok & 63;
    const float*    src = (mat == 0) ? WQ : (mat == 1) ? WK : (mat == 2) ? WV : WR;
    unsigned short* dst = (mat == 0) ? wqt : (mat == 1) ? wkt : (mat == 2) ? wvt : wrt;
    dst[l * 4096 + o * 64 + k] = f2b(src[l * 4096 + k * 64 + o]);
}

// ------- prep: W1 f32 [2496][512] -> bf16 fragment-linear w1p --------------------------
__global__ void w1pack(const float* __restrict__ W1, unsigned short* __restrict__ w1p)
{
    int t = blockIdx.x * 256 + threadIdx.x;        // 624*256 = 159744 = 2496*64
    int lane = t & 63, grp = t >> 6;               // grp 0..2495
    int ot = grp / 78, kk = grp % 78;
    int q = lane >> 4, n = ot * 16 + (lane & 15);
    int kb = kk * 32 + q * 8;
    unsigned short* dst = w1p + grp * 512 + lane * 8;
    #pragma unroll
    for (int j = 0; j < 8; ++j)
        dst[j] = f2b(W1[(kb + j) * 512 + n]);
}

// ------- prep: W2 f32 [512][256] -> bf16 fragment-linear w2p ---------------------------
__global__ void w2pack(const float* __restrict__ W2, unsigned short* __restrict__ w2p)
{
    int t = blockIdx.x * 256 + threadIdx.x;        // 64*256 = 16384 = 256*64
    int lane = t & 63, grp = t >> 6;               // grp 0..255
    int ot = grp / 16, kk = grp % 16;
    int q = lane >> 4, n = ot * 16 + (lane & 15);
    int kb = kk * 32 + q * 8;
    unsigned short* dst = w2p + grp * 512 + lane * 8;
    #pragma unroll
    for (int j = 0; j < 8; ++j)
        dst[j] = f2b(W2[(kb + j) * 256 + n]);
}

// ------- fused attention (ROUND-10 VERBATIM) ------------------------------------------
// block = 256 thr (4 waves), 2 samples/block; wave = (sample, head).
// LDS: xs 13824 + arena 4x9472 + red 16 = 51728 B  -> 3 blocks/CU (LDS-limited).
__global__ void __launch_bounds__(256) attn_kernel(
    const int* __restrict__ X,
    const float* __restrict__ embf,
    const unsigned short* __restrict__ wqt,
    const unsigned short* __restrict__ wkt,
    const unsigned short* __restrict__ wvt,
    const unsigned short* __restrict__ wrt,
    const float* __restrict__ wlinf,
    float* __restrict__ att_out)
{
    __shared__ unsigned short xs[2][48 * 72];      // [sample][token 48][col 64+8pad]
    __shared__ unsigned short arena[4][4736];
    __shared__ float red[4];

    const int tid  = threadIdx.x;
    const int wid  = tid >> 6;
    const int lane = tid & 63;
    const int sl   = wid >> 1;          // sample-in-block
    const int h    = wid & 1;           // head
    const int quad = lane >> 4;
    const int l16  = lane & 15;
    const int samp = blockIdx.x * 2 + sl;

    unsigned short* xss = xs[sl];
    unsigned short* qs  = arena[wid];
    unsigned short* ks  = qs + 1920;
    unsigned short* Ps  = qs;           // alias (qs/ks dead after S^T)
    unsigned short* vt  = qs + 3456;    // 32 x 40 (toks of one K-half)

    // ---- embedding gather: wave fills its sample's cols h*32..h*32+31 -----------------
    {
        const int tq = lane >> 4;            // 0..3
        const int cp = (lane & 15) * 2;      // 0,2,..,30
        const int col = h * 32 + cp;
        const int* xrow = X + samp * NF;
        #pragma unroll
        for (int t0 = 0; t0 < 48; t0 += 4) {
            int t = t0 + tq;
            unsigned pk = 0;
            if (t < NF) {
                int row = xrow[t] + t * VOCAB;
                const float2 v = *(const float2*)&embf[row * EMB + col];
                pk = cvt_pk(v.x, v.y);
            }
            *(unsigned*)&xss[t * 72 + col] = pk;   // rows 39..47 zeroed
        }
    }
    __syncthreads();

    for (int layer = 0; layer < NLAYER; ++layer) {
        const unsigned short* wq  = wqt + layer * 4096;
        const unsigned short* wk  = wkt + layer * 4096;
        const unsigned short* wvp = wvt + layer * 4096;
        const unsigned short* wr  = wrt + layer * 4096;

        // ---- Q,K projections (head h columns) -> qs, ks (row-major [tok][d]) ----------
        #pragma unroll
        for (int mat = 0; mat < 2; ++mat) {
            const unsigned short* wt = mat ? wk : wq;
            unsigned short* dst = mat ? ks : qs;
            #pragma unroll
            for (int mt = 0; mt < 3; ++mt) {
                #pragma unroll
                for (int nt = 0; nt < 2; ++nt) {
                    floatx4 c = {0.f, 0.f, 0.f, 0.f};
                    #pragma unroll
                    for (int kk = 0; kk < 2; ++kk) {
                        short8 a = ld8s(&xss[(mt * 16 + l16) * 72 + kk * 32 + quad * 8]);
                        short8 b = ld8s(&wt[(h * 32 + nt * 16 + l16) * 64 + kk * 32 + quad * 8]);
                        c = __builtin_amdgcn_mfma_f32_16x16x32_bf16(a, b, c, 0, 0, 0);
                    }
                    unsigned plo = cvt_pk(c[0], c[1]);
                    unsigned phi = cvt_pk(c[2], c[3]);
                    int base = (mt * 16 + quad * 4) * 40 + nt * 16 + l16;
                    dst[base]       = (unsigned short)plo;
                    dst[base + 40]  = (unsigned short)(plo >> 16);
                    dst[base + 80]  = (unsigned short)phi;
                    dst[base + 120] = (unsigned short)(phi >> 16);
                }
            }
        }

        // ---- S^T = K @ Q^T  (C row = j, col = i) — softmax dim j = C row dim ----------
        floatx4 ST[3][3];
        #pragma unroll
        for (int jt = 0; jt < 3; ++jt) {
            short8 a = ld8s(&ks[(jt * 16 + l16) * 40 + quad * 8]);
            #pragma unroll
            for (int it = 0; it < 3; ++it) {
                short8 b = ld8s(&qs[(it * 16 + l16) * 40 + quad * 8]);
                floatx4 z = {0.f, 0.f, 0.f, 0.f};
                ST[jt][it] = __builtin_amdgcn_mfma_f32_16x16x32_bf16(a, b, z, 0, 0, 0);
            }
        }

        // ---- softmax over j (local + shfl_xor 16,32); write P in A-layout to Ps -------
        #pragma unroll
        for (int it = 0; it < 3; ++it) {
            float p[3][4];
            float sum = 0.f;
            #pragma unroll
            for (int jt = 0; jt < 3; ++jt)
                #pragma unroll
                for (int r = 0; r < 4; ++r) {
                    int j = jt * 16 + quad * 4 + r;
                    float e = (j < NF) ? __expf(ST[jt][it][r]) : 0.f;
                    p[jt][r] = e;
                    sum += e;
                }
            sum += __shfl_xor(sum, 16, 64);
            sum += __shfl_xor(sum, 32, 64);
            float inv = 1.0f / sum;
            #pragma unroll
            for (int jt = 0; jt < 3; ++jt) {
                uint2 w;
                w.x = cvt_pk(p[jt][0] * inv, p[jt][1] * inv);
                w.y = cvt_pk(p[jt][2] * inv, p[jt][3] * inv);
                *(uint2*)&Ps[(it * 16 + l16) * 72 + jt * 16 + quad * 4] = w;
            }
            uint2 z2; z2.x = 0; z2.y = 0;                 // zero K-pad cols 48..63
            *(uint2*)&Ps[(it * 16 + l16) * 72 + 48 + quad * 4] = z2;
        }

        // ---- V projection: mt=0,1 -> vT (toks 0..31); mt=2 held in regs ---------------
        unsigned sv[2][2];      // [nt][lo/hi] packed mt=2 C-frag (toks 32..47)
        #pragma unroll
        for (int mt = 0; mt < 3; ++mt) {
            #pragma unroll
            for (int nt = 0; nt < 2; ++nt) {
                floatx4 c = {0.f, 0.f, 0.f, 0.f};
                #pragma unroll
                for (int kk = 0; kk < 2; ++kk) {
                    short8 a = ld8s(&xss[(mt * 16 + l16) * 72 + kk * 32 + quad * 8]);
                    short8 b = ld8s(&wvp[(h * 32 + nt * 16 + l16) * 64 + kk * 32 + quad * 8]);
                    c = __builtin_amdgcn_mfma_f32_16x16x32_bf16(a, b, c, 0, 0, 0);
                }
                unsigned lo = cvt_pk(c[0], c[1]);
                unsigned hi = cvt_pk(c[2], c[3]);
                if (mt < 2) {
                    uint2 w; w.x = lo; w.y = hi;      // vT[d][tok_local mt*16+quad*4 ..+3]
                    *(uint2*)&vt[(nt * 16 + l16) * 40 + mt * 16 + quad * 4] = w;
                } else {
                    sv[nt][0] = lo; sv[nt][1] = hi;
                }
            }
        }

        // ---- R projection -> O init ---------------------------------------------------
        floatx4 O[3][2];
        #pragma unroll
        for (int mt = 0; mt < 3; ++mt) {
            #pragma unroll
            for (int nt = 0; nt < 2; ++nt) {
                floatx4 c = {0.f, 0.f, 0.f, 0.f};
                #pragma unroll
                for (int kk = 0; kk < 2; ++kk) {
                    short8 a = ld8s(&xss[(mt * 16 + l16) * 72 + kk * 32 + quad * 8]);
                    short8 b = ld8s(&wr[(h * 32 + nt * 16 + l16) * 64 + kk * 32 + quad * 8]);
                    c = __builtin_amdgcn_mfma_f32_16x16x32_bf16(a, b, c, 0, 0, 0);
                }
                O[mt][nt] = c;
            }
        }

        __syncthreads();   // all waves done reading xs

        // ---- PV kk=0: toks 0..31 (A = Ps cols 0..31, B = vT) --------------------------
        {
            short8 a0 = ld8s(&Ps[(l16) * 72 + quad * 8]);
            short8 a1 = ld8s(&Ps[(16 + l16) * 72 + quad * 8]);
            short8 a2 = ld8s(&Ps[(32 + l16) * 72 + quad * 8]);
            #pragma unroll
            for (int nt = 0; nt < 2; ++nt) {
                short8 b = ld8s(&vt[(nt * 16 + l16) * 40 + quad * 8]);
                O[0][nt] = __builtin_amdgcn_mfma_f32_16x16x32_bf16(a0, b, O[0][nt], 0, 0, 0);
                O[1][nt] = __builtin_amdgcn_mfma_f32_16x16x32_bf16(a1, b, O[1][nt], 0, 0, 0);
                O[2][nt] = __builtin_amdgcn_mfma_f32_16x16x32_bf16(a2, b, O[2][nt], 0, 0, 0);
            }
        }
        // ---- refill vT with toks 32..63 (local 0..15 = sv, 16..31 = zeros) ------------
        #pragma unroll
        for (int nt = 0; nt < 2; ++nt) {
            uint2 w; w.x = sv[nt][0]; w.y = sv[nt][1];
            *(uint2*)&vt[(nt * 16 + l16) * 40 + quad * 4] = w;
            uint2 z; z.x = 0; z.y = 0;
            *(uint2*)&vt[(nt * 16 + l16) * 40 + 16 + quad * 4] = z;
        }
        // ---- PV kk=1: toks 32..63 (A = Ps cols 32..63) --------------------------------
        {
            short8 a0 = ld8s(&Ps[(l16) * 72 + 32 + quad * 8]);
            short8 a1 = ld8s(&Ps[(16 + l16) * 72 + 32 + quad * 8]);
            short8 a2 = ld8s(&Ps[(32 + l16) * 72 + 32 + quad * 8]);
            #pragma unroll
            for (int nt = 0; nt < 2; ++nt) {
                short8 b = ld8s(&vt[(nt * 16 + l16) * 40 + quad * 8]);
                O[0][nt] = __builtin_amdgcn_mfma_f32_16x16x32_bf16(a0, b, O[0][nt], 0, 0, 0);
                O[1][nt] = __builtin_amdgcn_mfma_f32_16x16x32_bf16(a1, b, O[1][nt], 0, 0, 0);
                O[2][nt] = __builtin_amdgcn_mfma_f32_16x16x32_bf16(a2, b, O[2][nt], 0, 0, 0);
            }
        }

        // ---- next x = relu(O + xWr); wave writes its head's 32 columns ----------------
        #pragma unroll
        for (int mt = 0; mt < 3; ++mt)
            #pragma unroll
            for (int nt = 0; nt < 2; ++nt) {
                unsigned plo = cvt_pk(fmaxf(O[mt][nt][0], 0.f), fmaxf(O[mt][nt][1], 0.f));
                unsigned phi = cvt_pk(fmaxf(O[mt][nt][2], 0.f), fmaxf(O[mt][nt][3], 0.f));
                int base = (mt * 16 + quad * 4) * 72 + h * 32 + nt * 16 + l16;
                xss[base]       = (unsigned short)plo;
                xss[base + 72]  = (unsigned short)(plo >> 16);
                xss[base + 144] = (unsigned short)phi;
                xss[base + 216] = (unsigned short)(phi >> 16);
            }

        __syncthreads();
    }

    // ---- att logit: relu( att_flat . Wlin ) -------------------------------------------
    {
        float acc = 0.f;
        const int c = lane & 31, tp = lane >> 5;
        const int col = h * 32 + c;
        for (int t0 = 0; t0 < 40; t0 += 2) {
            int t = t0 + tp;
            if (t < NF)
                acc += b2f(xss[t * 72 + col]) * wlinf[t * EMB + col];
        }
        #pragma unroll
        for (int off = 1; off < 64; off <<= 1)
            acc += __shfl_xor(acc, off, 64);
        if (lane == 0) red[wid] = acc;
        __syncthreads();
        if (tid < 2) {
            float v2 = red[tid * 2] + red[tid * 2 + 1];
            att_out[blockIdx.x * 2 + tid] = fmaxf(v2, 0.f);
        }
    }
}

// ------- DNN: 64-sample tile (round-6 structure, NO 2-arg launch_bounds) --------------
// 256 blocks x 256 thr. Packed coalesced B-loads. LDS: ea dbuf 18432 + h2s 33792
// = 52224 B. Phase 2 streams h1 through ea[0] in 8 owner-wave chunks.
__global__ void __launch_bounds__(256) dnn_kernel(
    const int* __restrict__ X,
    const float* __restrict__ embf,
    const unsigned short* __restrict__ w1p,
    const float* __restrict__ b1v,
    const unsigned short* __restrict__ w2p,
    const float* __restrict__ b2v,
    const float* __restrict__ w3v,
    const float* __restrict__ b3v,
    const float* __restrict__ att_in,
    float* __restrict__ out)
{
    __shared__ unsigned short ea[2][64 * 72];   // gather dbuf; ea[0] = phase-2 chunk buf
    __shared__ unsigned short h2s[64 * 264];    // h2 [64][256+8pad]

    const int tid  = threadIdx.x;
    const int wid  = tid >> 6, lane = tid & 63, quad = lane >> 4, l16 = lane & 15;
    const int S0   = blockIdx.x * 64;

    floatx4 C1[4][8];
    #pragma unroll
    for (int mt = 0; mt < 4; ++mt)
        #pragma unroll
        for (int nt = 0; nt < 8; ++nt)
            C1[mt][nt] = (floatx4){0.f, 0.f, 0.f, 0.f};

    const int gs = tid >> 2;        // 0..63 sample for staging
    const int gg = tid & 3;         // 16 floats each

    // prologue: stage field 0 into ea[0]
    {
        int row = X[(S0 + gs) * NF + 0];
        const float4* src = (const float4*)&embf[row * EMB + gg * 16];
        float4 v0 = src[0], v1 = src[1], v2 = src[2], v3 = src[3];
        uint4 u0, u1;
        u0.x = cvt_pk(v0.x, v0.y); u0.y = cvt_pk(v0.z, v0.w);
        u0.z = cvt_pk(v1.x, v1.y); u0.w = cvt_pk(v1.z, v1.w);
        u1.x = cvt_pk(v2.x, v2.y); u1.y = cvt_pk(v2.z, v2.w);
        u1.z = cvt_pk(v3.x, v3.y); u1.w = cvt_pk(v3.z, v3.w);
        *(uint4*)&ea[0][gs * 72 + gg * 16]     = u0;
        *(uint4*)&ea[0][gs * 72 + gg * 16 + 8] = u1;
    }
    __syncthreads();

    // ---- phase 1: h1 = emb(64 x 2496) @ W1, K streamed per field, dbuf (1 sync/iter) --
    for (int f = 0; f < NF; ++f) {
        if (f < NF - 1) {   // load + convert + stage next field into the other buffer
            int row = X[(S0 + gs) * NF + f + 1] + (f + 1) * VOCAB;
            const float4* src = (const float4*)&embf[row * EMB + gg * 16];
            float4 v0 = src[0], v1 = src[1], v2 = src[2], v3 = src[3];
            uint4 u0, u1;
            u0.x = cvt_pk(v0.x, v0.y); u0.y = cvt_pk(v0.z, v0.w);
            u0.z = cvt_pk(v1.x, v1.y); u0.w = cvt_pk(v1.z, v1.w);
            u1.x = cvt_pk(v2.x, v2.y); u1.y = cvt_pk(v2.z, v2.w);
            u1.z = cvt_pk(v3.x, v3.y); u1.w = cvt_pk(v3.z, v3.w);
            *(uint4*)&ea[(f + 1) & 1][gs * 72 + gg * 16]     = u0;
            *(uint4*)&ea[(f + 1) & 1][gs * 72 + gg * 16 + 8] = u1;
        }
        const unsigned short* eac = ea[f & 1];
        short8 a[4][2];
        #pragma unroll
        for (int mt = 0; mt < 4; ++mt) {
            a[mt][0] = ld8s(&eac[(mt * 16 + l16) * 72 + quad * 8]);
            a[mt][1] = ld8s(&eac[(mt * 16 + l16) * 72 + 32 + quad * 8]);
        }
        #pragma unroll
        for (int nt = 0; nt < 8; ++nt) {
            // packed, fully-coalesced B-frag loads (1KB/wave/inst)
            const unsigned short* bp = w1p + (((wid * 8 + nt) * 78 + f * 2) * 64 + lane) * 8;
            short8 b0 = ld8s(bp);
            short8 b1 = ld8s(bp + 512);
            #pragma unroll
            for (int mt = 0; mt < 4; ++mt) {
                C1[mt][nt] = __builtin_amdgcn_mfma_f32_16x16x32_bf16(a[mt][0], b0, C1[mt][nt], 0, 0, 0);
                C1[mt][nt] = __builtin_amdgcn_mfma_f32_16x16x32_bf16(a[mt][1], b1, C1[mt][nt], 0, 0, 0);
            }
        }
        __syncthreads();   // waves may not drift >1 iter: protects both ea buffers
    }

    // ---- phase 2: h2 = h1(64 x 512) @ W2; h1 streamed through ea[0] in 8 chunks -------
    floatx4 C2[4][4];
    #pragma unroll
    for (int mt = 0; mt < 4; ++mt)
        #pragma unroll
        for (int nt = 0; nt < 4; ++nt)
            C2[mt][nt] = (floatx4){0.f, 0.f, 0.f, 0.f};

    unsigned short* cb = ea[0];
    for (int ch = 0; ch < 8; ++ch) {
        if (wid == (ch >> 1)) {
            int ntl0 = (ch & 1) * 4;
            #pragma unroll
            for (int i = 0; i < 4; ++i) {
                float bb = b1v[wid * 128 + (ntl0 + i) * 16 + l16];
                #pragma unroll
                for (int mt = 0; mt < 4; ++mt)
                    #pragma unroll
                    for (int r = 0; r < 4; ++r)
                        cb[(mt * 16 + quad * 4 + r) * 72 + i * 16 + l16] =
                            f2b(fmaxf(C1[mt][ntl0 + i][r] + bb, 0.f));
            }
        }
        __syncthreads();
        short8 a2[4][2];
        #pragma unroll
        for (int mt = 0; mt < 4; ++mt) {
            a2[mt][0] = ld8s(&cb[(mt * 16 + l16) * 72 + quad * 8]);
            a2[mt][1] = ld8s(&cb[(mt * 16 + l16) * 72 + 32 + quad * 8]);
        }
        #pragma unroll
        for (int nt = 0; nt < 4; ++nt) {
            const unsigned short* bp = w2p + (((wid * 4 + nt) * 16 + ch * 2) * 64 + lane) * 8;
            short8 b0 = ld8s(bp);
            short8 b1 = ld8s(bp + 512);
            #pragma unroll
            for (int mt = 0; mt < 4; ++mt) {
                C2[mt][nt] = __builtin_amdgcn_mfma_f32_16x16x32_bf16(a2[mt][0], b0, C2[mt][nt], 0, 0, 0);
                C2[mt][nt] = __builtin_amdgcn_mfma_f32_16x16x32_bf16(a2[mt][1], b1, C2[mt][nt], 0, 0, 0);
            }
        }
        __syncthreads();
    }

    // h2 -> LDS (f32 bias + relu, stored bf16)
    #pragma unroll
    for (int nt = 0; nt < 4; ++nt) {
        float bb = b2v[wid * 64 + nt * 16 + l16];
        #pragma unroll
        for (int mt = 0; mt < 4; ++mt)
            #pragma unroll
            for (int r = 0; r < 4; ++r)
                h2s[(mt * 16 + quad * 4 + r) * 264 + wid * 64 + nt * 16 + l16] =
                    f2b(fmaxf(C2[mt][nt][r] + bb, 0.f));
    }
    __syncthreads();

    // ---- phase 3: dnn = relu(h2 . W3 + b3); out = sigmoid(att + dnn), f32 -------------
    {
        int s = tid >> 2, part = tid & 3;     // 4 lanes per sample, 64 elems each
        float acc = 0.f;
        #pragma unroll 8
        for (int j = 0; j < 64; ++j) {
            int jj = part * 64 + j;
            acc += b2f(h2s[s * 264 + jj]) * w3v[jj];
        }
        acc += __shfl_xor(acc, 1, 64);
        acc += __shfl_xor(acc, 2, 64);
        if (part == 0) {
            float dnn = fmaxf(acc + b3v[0], 0.f);
            float v = dnn + att_in[S0 + s];
            out[S0 + s] = 1.f / (1.f + __expf(-v));
        }
    }
}

extern "C" void kernel_launch(void* const* d_in, const int* in_sizes, int n_in,
                              void* d_out, int out_size, void* d_ws, size_t ws_size,
                              hipStream_t stream)
{
    (void)in_sizes; (void)n_in; (void)out_size; (void)ws_size;

    const int*   X    = (const int*)d_in[0];
    const float* emb  = (const float*)d_in[1];
    const float* WQ   = (const float*)d_in[2];
    const float* WK   = (const float*)d_in[3];
    const float* WV   = (const float*)d_in[4];
    const float* WR   = (const float*)d_in[5];
    const float* W1   = (const float*)d_in[6];
    const float* b1   = (const float*)d_in[7];
    const float* W2   = (const float*)d_in[8];
    const float* b2   = (const float*)d_in[9];
    const float* W3   = (const float*)d_in[10];
    const float* b3   = (const float*)d_in[11];
    const float* Wlin = (const float*)d_in[12];

    char* ws = (char*)d_ws;
    float*          att_logit = (float*)ws;                          // 16384 f32 = 64KB
    unsigned short* wqt = (unsigned short*)(ws + 65536);             // 3*4096 shorts each
    unsigned short* wkt = wqt + 3 * 4096;
    unsigned short* wvt = wkt + 3 * 4096;
    unsigned short* wrt = wvt + 3 * 4096;
    unsigned short* w1p = wrt + 3 * 4096;                            // 2496*512 shorts
    unsigned short* w2p = w1p + 2496 * 512;                          // 256*512 shorts

    attw_t<<<192, 256, 0, stream>>>(WQ, WK, WV, WR, wqt, wkt, wvt, wrt);
    w1pack<<<624, 256, 0, stream>>>(W1, w1p);
    w2pack<<<64, 256, 0, stream>>>(W2, w2p);
    attn_kernel<<<8192, 256, 0, stream>>>(X, emb, wqt, wkt, wvt, wrt, Wlin, att_logit);
    dnn_kernel<<<256, 256, 0, stream>>>(X, emb, w1p, b1, w2p, b2, W3, b3, att_logit,
                                        (float*)d_out);
}

// Round 13
// 414.001 us; speedup vs baseline: 1.5116x; 1.5116x over previous
//
#include <hip/hip_runtime.h>
#include <hip/hip_bf16.h>

// AutoInt+MLP fused forward, MI355X gfx950.  Round 13:
//  - dnn : M=64 verdict final — spills intrinsically (r12: VGPR 140, 1.3GB scratch
//          writes even without launch_bounds). Round-10 M=32 dnn restored verbatim.
//  - attn: transpose-oriented projections. Q/K proj computed as W^T@x^T (operand
//          swap; A/B frags share lane addressing) so C cols=tok, rows=4 consecutive
//          d -> qs/ks [tok][d] written with b64 (was 4x u16). R+PV computed as
//          O^T = V^T@P^T (A=vt, B=Ps — same LDS addresses as before, swapped) so
//          x writeback is b64 too. 72 scalar u16 stores/wave/layer -> 18 b64.
//  HARD RULES: no 2-arg __launch_bounds__; no heterogeneous-role merged dispatch.

#define NF     39
#define EMB    64
#define NLAYER 3
#define VOCAB  1000
#define FLAT   2496
#define H1     512
#define H2     256

typedef __attribute__((ext_vector_type(8))) short  short8;
typedef __attribute__((ext_vector_type(4))) float  floatx4;

__device__ __forceinline__ short8 ld8s(const unsigned short* p) {
    return *(const short8*)p;
}
__device__ __forceinline__ float b2f(unsigned short h) {
    union { unsigned u; float f; } x; x.u = ((unsigned)h) << 16; return x.f;
}
__device__ __forceinline__ unsigned short f2b(float f) {
    union { float f; unsigned u; } x; x.f = f;
    unsigned u = x.u;
    return (unsigned short)((u + 0x7fffu + ((u >> 16) & 1u)) >> 16);
}
// 2 floats -> packed bf16x2 in ONE VALU op (gfx950 hw cvt, RNE)
__device__ __forceinline__ unsigned cvt_pk(float a, float b) {
#if defined(__gfx950__)
    unsigned r;
    asm("v_cvt_pk_bf16_f32 %0, %1, %2" : "=v"(r) : "v"(a), "v"(b));
    return r;
#else
    return (unsigned)f2b(a) | ((unsigned)f2b(b) << 16);
#endif
}

// ------- prep: attention weights f32 [L][64(k)][64(o)] -> bf16 [L][o][k] --------------
__global__ void attw_t(const float* __restrict__ WQ, const float* __restrict__ WK,
                       const float* __restrict__ WV, const float* __restrict__ WR,
                       unsigned short* __restrict__ wqt, unsigned short* __restrict__ wkt,
                       unsigned short* __restrict__ wvt, unsigned short* __restrict__ wrt)
{
    int idx = blockIdx.x * 256 + threadIdx.x;       // 4*3*4096 = 49152
    if (idx >= 4 * 3 * 4096) return;
    int mat = idx / 12288;
    int rem = idx % 12288;
    int l   = rem / 4096;
    int ok  = rem % 4096;
    int o = ok >> 6, k = ok & 63;
    const float*    src = (mat == 0) ? WQ : (mat == 1) ? WK : (mat == 2) ? WV : WR;
    unsigned short* dst = (mat == 0) ? wqt : (mat == 1) ? wkt : (mat == 2) ? wvt : wrt;
    dst[l * 4096 + o * 64 + k] = f2b(src[l * 4096 + k * 64 + o]);
}

// ------- prep: W1 f32 [2496][512] -> bf16 fragment-linear w1p --------------------------
__global__ void w1pack(const float* __restrict__ W1, unsigned short* __restrict__ w1p)
{
    int t = blockIdx.x * 256 + threadIdx.x;        // 624*256 = 159744 = 2496*64
    int lane = t & 63, grp = t >> 6;               // grp 0..2495
    int ot = grp / 78, kk = grp % 78;
    int q = lane >> 4, n = ot * 16 + (lane & 15);
    int kb = kk * 32 + q * 8;
    unsigned short* dst = w1p + grp * 512 + lane * 8;
    #pragma unroll
    for (int j = 0; j < 8; ++j)
        dst[j] = f2b(W1[(kb + j) * 512 + n]);
}

// ------- prep: W2 f32 [512][256] -> bf16 fragment-linear w2p ---------------------------
__global__ void w2pack(const float* __restrict__ W2, unsigned short* __restrict__ w2p)
{
    int t = blockIdx.x * 256 + threadIdx.x;        // 64*256 = 16384 = 256*64
    int lane = t & 63, grp = t >> 6;               // grp 0..255
    int ot = grp / 16, kk = grp % 16;
    int q = lane >> 4, n = ot * 16 + (lane & 15);
    int kb = kk * 32 + q * 8;
    unsigned short* dst = w2p + grp * 512 + lane * 8;
    #pragma unroll
    for (int j = 0; j < 8; ++j)
        dst[j] = f2b(W2[(kb + j) * 256 + n]);
}

// ------- fused attention: embed + 3 MHSA layers + Wlin logit --------------------------
// block = 256 thr (4 waves), 2 samples/block; wave = (sample, head).
// LDS: xs 13824 + arena 4x9472 + red 16 = 51728 B  -> 3 blocks/CU (LDS-limited).
// Per-wave arena (4736 shorts): [qs 0..1920 | ks 1920..3840] (dead after S^T),
// overlaid by [Ps 0..3456 | vT 3456..4736 (32d x 40, one 32-token K-half)].
__global__ void __launch_bounds__(256) attn_kernel(
    const int* __restrict__ X,
    const float* __restrict__ embf,
    const unsigned short* __restrict__ wqt,
    const unsigned short* __restrict__ wkt,
    const unsigned short* __restrict__ wvt,
    const unsigned short* __restrict__ wrt,
    const float* __restrict__ wlinf,
    float* __restrict__ att_out)
{
    __shared__ unsigned short xs[2][48 * 72];      // [sample][token 48][col 64+8pad]
    __shared__ unsigned short arena[4][4736];
    __shared__ float red[4];

    const int tid  = threadIdx.x;
    const int wid  = tid >> 6;
    const int lane = tid & 63;
    const int sl   = wid >> 1;          // sample-in-block
    const int h    = wid & 1;           // head
    const int quad = lane >> 4;
    const int l16  = lane & 15;
    const int samp = blockIdx.x * 2 + sl;

    unsigned short* xss = xs[sl];
    unsigned short* qs  = arena[wid];
    unsigned short* ks  = qs + 1920;
    unsigned short* Ps  = qs;           // alias (qs/ks dead after S^T)
    unsigned short* vt  = qs + 3456;    // 32 x 40 (toks of one K-half)

    // ---- embedding gather: wave fills its sample's cols h*32..h*32+31 -----------------
    {
        const int tq = lane >> 4;            // 0..3
        const int cp = (lane & 15) * 2;      // 0,2,..,30
        const int col = h * 32 + cp;
        const int* xrow = X + samp * NF;
        #pragma unroll
        for (int t0 = 0; t0 < 48; t0 += 4) {
            int t = t0 + tq;
            unsigned pk = 0;
            if (t < NF) {
                int row = xrow[t] + t * VOCAB;
                const float2 v = *(const float2*)&embf[row * EMB + col];
                pk = cvt_pk(v.x, v.y);
            }
            *(unsigned*)&xss[t * 72 + col] = pk;   // rows 39..47 zeroed
        }
    }
    __syncthreads();

    for (int layer = 0; layer < NLAYER; ++layer) {
        const unsigned short* wq  = wqt + layer * 4096;
        const unsigned short* wk  = wkt + layer * 4096;
        const unsigned short* wvp = wvt + layer * 4096;
        const unsigned short* wr  = wrt + layer * 4096;

        // ---- Q,K projections, TRANSPOSED orientation: C = W^T @ x^T -------------------
        // A = weight [m=out][k=in] (wt rows, contiguous); B = xss [n=tok][k=in].
        // C: row = out ot*16+quad*4+r, col = tok tt*16+l16  -> qs/ks[tok][d] b64 store.
        #pragma unroll
        for (int mat = 0; mat < 2; ++mat) {
            const unsigned short* wt = mat ? wk : wq;
            unsigned short* dst = mat ? ks : qs;
            #pragma unroll
            for (int ot = 0; ot < 2; ++ot) {
                #pragma unroll
                for (int tt = 0; tt < 3; ++tt) {
                    floatx4 c = {0.f, 0.f, 0.f, 0.f};
                    #pragma unroll
                    for (int kk = 0; kk < 2; ++kk) {
                        short8 a = ld8s(&wt[(h * 32 + ot * 16 + l16) * 64 + kk * 32 + quad * 8]);
                        short8 b = ld8s(&xss[(tt * 16 + l16) * 72 + kk * 32 + quad * 8]);
                        c = __builtin_amdgcn_mfma_f32_16x16x32_bf16(a, b, c, 0, 0, 0);
                    }
                    uint2 w;
                    w.x = cvt_pk(c[0], c[1]);
                    w.y = cvt_pk(c[2], c[3]);
                    *(uint2*)&dst[(tt * 16 + l16) * 40 + ot * 16 + quad * 4] = w;
                }
            }
        }

        // ---- S^T = K @ Q^T  (C row = j, col = i) — softmax dim j = C row dim ----------
        floatx4 ST[3][3];
        #pragma unroll
        for (int jt = 0; jt < 3; ++jt) {
            short8 a = ld8s(&ks[(jt * 16 + l16) * 40 + quad * 8]);
            #pragma unroll
            for (int it = 0; it < 3; ++it) {
                short8 b = ld8s(&qs[(it * 16 + l16) * 40 + quad * 8]);
                floatx4 z = {0.f, 0.f, 0.f, 0.f};
                ST[jt][it] = __builtin_amdgcn_mfma_f32_16x16x32_bf16(a, b, z, 0, 0, 0);
            }
        }

        // ---- softmax over j (local + shfl_xor 16,32); write P in [i][j] to Ps ---------
        #pragma unroll
        for (int it = 0; it < 3; ++it) {
            float p[3][4];
            float sum = 0.f;
            #pragma unroll
            for (int jt = 0; jt < 3; ++jt)
                #pragma unroll
                for (int r = 0; r < 4; ++r) {
                    int j = jt * 16 + quad * 4 + r;
                    float e = (j < NF) ? __expf(ST[jt][it][r]) : 0.f;
                    p[jt][r] = e;
                    sum += e;
                }
            sum += __shfl_xor(sum, 16, 64);
            sum += __shfl_xor(sum, 32, 64);
            float inv = 1.0f / sum;
            #pragma unroll
            for (int jt = 0; jt < 3; ++jt) {
                uint2 w;
                w.x = cvt_pk(p[jt][0] * inv, p[jt][1] * inv);
                w.y = cvt_pk(p[jt][2] * inv, p[jt][3] * inv);
                *(uint2*)&Ps[(it * 16 + l16) * 72 + jt * 16 + quad * 4] = w;
            }
            uint2 z2; z2.x = 0; z2.y = 0;                 // zero K-pad cols 48..63
            *(uint2*)&Ps[(it * 16 + l16) * 72 + 48 + quad * 4] = z2;
        }

        // ---- V projection (original orientation): mt=0,1 -> vT (toks 0..31); mt=2 regs
        unsigned sv[2][2];      // [nt][lo/hi] packed mt=2 C-frag (toks 32..47)
        #pragma unroll
        for (int mt = 0; mt < 3; ++mt) {
            #pragma unroll
            for (int nt = 0; nt < 2; ++nt) {
                floatx4 c = {0.f, 0.f, 0.f, 0.f};
                #pragma unroll
                for (int kk = 0; kk < 2; ++kk) {
                    short8 a = ld8s(&xss[(mt * 16 + l16) * 72 + kk * 32 + quad * 8]);
                    short8 b = ld8s(&wvp[(h * 32 + nt * 16 + l16) * 64 + kk * 32 + quad * 8]);
                    c = __builtin_amdgcn_mfma_f32_16x16x32_bf16(a, b, c, 0, 0, 0);
                }
                unsigned lo = cvt_pk(c[0], c[1]);
                unsigned hi = cvt_pk(c[2], c[3]);
                if (mt < 2) {
                    uint2 w; w.x = lo; w.y = hi;      // vT[d][tok_local mt*16+quad*4 ..+3]
                    *(uint2*)&vt[(nt * 16 + l16) * 40 + mt * 16 + quad * 4] = w;
                } else {
                    sv[nt][0] = lo; sv[nt][1] = hi;
                }
            }
        }

        // ---- R projection, TRANSPOSED: O^T init (row = d, col = tok) ------------------
        floatx4 O[2][3];        // [dt][it]
        #pragma unroll
        for (int dt = 0; dt < 2; ++dt) {
            #pragma unroll
            for (int it = 0; it < 3; ++it) {
                floatx4 c = {0.f, 0.f, 0.f, 0.f};
                #pragma unroll
                for (int kk = 0; kk < 2; ++kk) {
                    short8 a = ld8s(&wr[(h * 32 + dt * 16 + l16) * 64 + kk * 32 + quad * 8]);
                    short8 b = ld8s(&xss[(it * 16 + l16) * 72 + kk * 32 + quad * 8]);
                    c = __builtin_amdgcn_mfma_f32_16x16x32_bf16(a, b, c, 0, 0, 0);
                }
                O[dt][it] = c;
            }
        }

        __syncthreads();   // all waves done reading xs

        // ---- O^T += V^T @ P^T, kk=0 (toks 0..31): A = vt, B = Ps ----------------------
        {
            short8 b0 = ld8s(&Ps[(l16) * 72 + quad * 8]);
            short8 b1 = ld8s(&Ps[(16 + l16) * 72 + quad * 8]);
            short8 b2 = ld8s(&Ps[(32 + l16) * 72 + quad * 8]);
            #pragma unroll
            for (int dt = 0; dt < 2; ++dt) {
                short8 a = ld8s(&vt[(dt * 16 + l16) * 40 + quad * 8]);
                O[dt][0] = __builtin_amdgcn_mfma_f32_16x16x32_bf16(a, b0, O[dt][0], 0, 0, 0);
                O[dt][1] = __builtin_amdgcn_mfma_f32_16x16x32_bf16(a, b1, O[dt][1], 0, 0, 0);
                O[dt][2] = __builtin_amdgcn_mfma_f32_16x16x32_bf16(a, b2, O[dt][2], 0, 0, 0);
            }
        }
        // ---- refill vT with toks 32..63 (local 0..15 = sv, 16..31 = zeros) ------------
        #pragma unroll
        for (int nt = 0; nt < 2; ++nt) {
            uint2 w; w.x = sv[nt][0]; w.y = sv[nt][1];
            *(uint2*)&vt[(nt * 16 + l16) * 40 + quad * 4] = w;
            uint2 z; z.x = 0; z.y = 0;
            *(uint2*)&vt[(nt * 16 + l16) * 40 + 16 + quad * 4] = z;
        }
        // ---- O^T += V^T @ P^T, kk=1 (toks 32..63) -------------------------------------
        {
            short8 b0 = ld8s(&Ps[(l16) * 72 + 32 + quad * 8]);
            short8 b1 = ld8s(&Ps[(16 + l16) * 72 + 32 + quad * 8]);
            short8 b2 = ld8s(&Ps[(32 + l16) * 72 + 32 + quad * 8]);
            #pragma unroll
            for (int dt = 0; dt < 2; ++dt) {
                short8 a = ld8s(&vt[(dt * 16 + l16) * 40 + quad * 8]);
                O[dt][0] = __builtin_amdgcn_mfma_f32_16x16x32_bf16(a, b0, O[dt][0], 0, 0, 0);
                O[dt][1] = __builtin_amdgcn_mfma_f32_16x16x32_bf16(a, b1, O[dt][1], 0, 0, 0);
                O[dt][2] = __builtin_amdgcn_mfma_f32_16x16x32_bf16(a, b2, O[dt][2], 0, 0, 0);
            }
        }

        // ---- next x = relu(O^T + ...): C row = d dt*16+quad*4+r, col = tok it*16+l16 --
        // write xss[tok][d]: b64 of 4 consecutive d.
        #pragma unroll
        for (int dt = 0; dt < 2; ++dt)
            #pragma unroll
            for (int it = 0; it < 3; ++it) {
                uint2 w;
                w.x = cvt_pk(fmaxf(O[dt][it][0], 0.f), fmaxf(O[dt][it][1], 0.f));
                w.y = cvt_pk(fmaxf(O[dt][it][2], 0.f), fmaxf(O[dt][it][3], 0.f));
                *(uint2*)&xss[(it * 16 + l16) * 72 + h * 32 + dt * 16 + quad * 4] = w;
            }

        __syncthreads();
    }

    // ---- att logit: relu( att_flat . Wlin ) -------------------------------------------
    {
        float acc = 0.f;
        const int c = lane & 31, tp = lane >> 5;
        const int col = h * 32 + c;
        for (int t0 = 0; t0 < 40; t0 += 2) {
            int t = t0 + tp;
            if (t < NF)
                acc += b2f(xss[t * 72 + col]) * wlinf[t * EMB + col];
        }
        #pragma unroll
        for (int off = 1; off < 64; off <<= 1)
            acc += __shfl_xor(acc, off, 64);
        if (lane == 0) red[wid] = acc;
        __syncthreads();
        if (tid < 2) {
            float v2 = red[tid * 2] + red[tid * 2 + 1];
            att_out[blockIdx.x * 2 + tid] = fmaxf(v2, 0.f);
        }
    }
}

// ------- DNN (ROUND-10 VERBATIM): 32-sample tile, packed B-loads ----------------------
// 512 blocks x 256 thr. LDS: ea 9216 + h1s 33280 = 42496 B.
__global__ void __launch_bounds__(256) dnn_kernel(
    const int* __restrict__ X,
    const float* __restrict__ embf,
    const unsigned short* __restrict__ w1p,
    const float* __restrict__ b1v,
    const unsigned short* __restrict__ w2p,
    const float* __restrict__ b2v,
    const float* __restrict__ w3v,
    const float* __restrict__ b3v,
    const float* __restrict__ att_in,
    float* __restrict__ out)
{
    __shared__ unsigned short ea[2][32 * 72];     // double-buffered [sample 32][64+8pad]
    __shared__ unsigned short h1s[32 * 520];      // h1 [32][512+8pad]; h2 [32][264] aliases
    unsigned short* h2s = h1s;

    const int tid  = threadIdx.x;
    const int wid  = tid >> 6, lane = tid & 63, quad = lane >> 4, l16 = lane & 15;
    const int S0   = blockIdx.x * 32;

    floatx4 C1[2][8];
    #pragma unroll
    for (int mt = 0; mt < 2; ++mt)
        #pragma unroll
        for (int nt = 0; nt < 8; ++nt)
            C1[mt][nt] = (floatx4){0.f, 0.f, 0.f, 0.f};

    const int gs = tid >> 3;        // 0..31 sample for staging
    const int gg = tid & 7;         // 8 floats each

    // prologue: stage field 0 into ea[0]
    {
        int row = X[(S0 + gs) * NF + 0];
        const float4* src = (const float4*)&embf[row * EMB + gg * 8];
        float4 v0 = src[0], v1 = src[1];
        uint4 u;
        u.x = cvt_pk(v0.x, v0.y); u.y = cvt_pk(v0.z, v0.w);
        u.z = cvt_pk(v1.x, v1.y); u.w = cvt_pk(v1.z, v1.w);
        *(uint4*)&ea[0][gs * 72 + gg * 8] = u;
    }
    __syncthreads();

    // ---- phase 1: h1 = emb(32 x 2496) @ W1, K streamed per field, dbuf, 1 sync/iter ---
    for (int f = 0; f < NF; ++f) {
        if (f < NF - 1) {   // stage next field into the other buffer (disjoint from reads)
            int row = X[(S0 + gs) * NF + f + 1] + (f + 1) * VOCAB;
            const float4* src = (const float4*)&embf[row * EMB + gg * 8];
            float4 v0 = src[0], v1 = src[1];
            uint4 u;
            u.x = cvt_pk(v0.x, v0.y); u.y = cvt_pk(v0.z, v0.w);
            u.z = cvt_pk(v1.x, v1.y); u.w = cvt_pk(v1.z, v1.w);
            *(uint4*)&ea[(f + 1) & 1][gs * 72 + gg * 8] = u;
        }
        const unsigned short* eac = ea[f & 1];
        short8 a[2][2];
        #pragma unroll
        for (int mt = 0; mt < 2; ++mt) {
            a[mt][0] = ld8s(&eac[(mt * 16 + l16) * 72 + quad * 8]);
            a[mt][1] = ld8s(&eac[(mt * 16 + l16) * 72 + 32 + quad * 8]);
        }
        #pragma unroll
        for (int nt = 0; nt < 8; ++nt) {
            const unsigned short* bp = w1p + (((wid * 8 + nt) * 78 + f * 2) * 64 + lane) * 8;
            short8 b0 = ld8s(bp);
            short8 b1 = ld8s(bp + 512);
            #pragma unroll
            for (int mt = 0; mt < 2; ++mt) {
                C1[mt][nt] = __builtin_amdgcn_mfma_f32_16x16x32_bf16(a[mt][0], b0, C1[mt][nt], 0, 0, 0);
                C1[mt][nt] = __builtin_amdgcn_mfma_f32_16x16x32_bf16(a[mt][1], b1, C1[mt][nt], 0, 0, 0);
            }
        }
        __syncthreads();   // waves may not drift >1 iter: protects both ea buffers
    }

    // bias + relu, write ALL of h1 to LDS (each wave owns 128 cols)
    #pragma unroll
    for (int nt = 0; nt < 8; ++nt) {
        float bb = b1v[wid * 128 + nt * 16 + l16];
        #pragma unroll
        for (int mt = 0; mt < 2; ++mt) {
            #pragma unroll
            for (int r = 0; r < 4; ++r) {
                float v = fmaxf(C1[mt][nt][r] + bb, 0.f);
                h1s[(mt * 16 + quad * 4 + r) * 520 + wid * 128 + nt * 16 + l16] = f2b(v);
            }
        }
    }
    __syncthreads();

    // ---- phase 2: h2 = h1(32 x 512) @ W2, single pass, wave owns 64 N-cols ------------
    floatx4 C2[2][4];
    #pragma unroll
    for (int mt = 0; mt < 2; ++mt)
        #pragma unroll
        for (int nt = 0; nt < 4; ++nt)
            C2[mt][nt] = (floatx4){0.f, 0.f, 0.f, 0.f};

    #pragma unroll 4
    for (int kk = 0; kk < 16; ++kk) {
        short8 a0 = ld8s(&h1s[(l16) * 520 + kk * 32 + quad * 8]);
        short8 a1 = ld8s(&h1s[(16 + l16) * 520 + kk * 32 + quad * 8]);
        #pragma unroll
        for (int nt = 0; nt < 4; ++nt) {
            short8 b = ld8s(w2p + (((wid * 4 + nt) * 16 + kk) * 64 + lane) * 8);
            C2[0][nt] = __builtin_amdgcn_mfma_f32_16x16x32_bf16(a0, b, C2[0][nt], 0, 0, 0);
            C2[1][nt] = __builtin_amdgcn_mfma_f32_16x16x32_bf16(a1, b, C2[1][nt], 0, 0, 0);
        }
    }
    __syncthreads();    // h1 reads complete -> safe to alias h2s onto h1s

    #pragma unroll
    for (int nt = 0; nt < 4; ++nt) {
        float bb = b2v[wid * 64 + nt * 16 + l16];
        #pragma unroll
        for (int mt = 0; mt < 2; ++mt)
            #pragma unroll
            for (int r = 0; r < 4; ++r)
                h2s[(mt * 16 + quad * 4 + r) * 264 + wid * 64 + nt * 16 + l16] =
                    f2b(fmaxf(C2[mt][nt][r] + bb, 0.f));
    }
    __syncthreads();

    // ---- phase 3: dnn = relu(h2 . W3 + b3); out = sigmoid(att + dnn), f32 -------------
    {
        int s = tid >> 3, part = tid & 7;     // 8 lanes per sample, 32 elems each
        float acc = 0.f;
        #pragma unroll 8
        for (int j = 0; j < 32; ++j) {
            int jj = part * 32 + j;
            acc += b2f(h2s[s * 264 + jj]) * w3v[jj];
        }
        acc += __shfl_xor(acc, 1, 64);
        acc += __shfl_xor(acc, 2, 64);
        acc += __shfl_xor(acc, 4, 64);
        if (part == 0) {
            float dnn = fmaxf(acc + b3v[0], 0.f);
            float v = dnn + att_in[S0 + s];
            out[S0 + s] = 1.f / (1.f + __expf(-v));
        }
    }
}

extern "C" void kernel_launch(void* const* d_in, const int* in_sizes, int n_in,
                              void* d_out, int out_size, void* d_ws, size_t ws_size,
                              hipStream_t stream)
{
    (void)in_sizes; (void)n_in; (void)out_size; (void)ws_size;

    const int*   X    = (const int*)d_in[0];
    const float* emb  = (const float*)d_in[1];
    const float* WQ   = (const float*)d_in[2];
    const float* WK   = (const float*)d_in[3];
    const float* WV   = (const float*)d_in[4];
    const float* WR   = (const float*)d_in[5];
    const float* W1   = (const float*)d_in[6];
    const float* b1   = (const float*)d_in[7];
    const float* W2   = (const float*)d_in[8];
    const float* b2   = (const float*)d_in[9];
    const float* W3   = (const float*)d_in[10];
    const float* b3   = (const float*)d_in[11];
    const float* Wlin = (const float*)d_in[12];

    char* ws = (char*)d_ws;
    float*          att_logit = (float*)ws;                          // 16384 f32 = 64KB
    unsigned short* wqt = (unsigned short*)(ws + 65536);             // 3*4096 shorts each
    unsigned short* wkt = wqt + 3 * 4096;
    unsigned short* wvt = wkt + 3 * 4096;
    unsigned short* wrt = wvt + 3 * 4096;
    unsigned short* w1p = wrt + 3 * 4096;                            // 2496*512 shorts
    unsigned short* w2p = w1p + 2496 * 512;                          // 256*512 shorts

    attw_t<<<192, 256, 0, stream>>>(WQ, WK, WV, WR, wqt, wkt, wvt, wrt);
    w1pack<<<624, 256, 0, stream>>>(W1, w1p);
    w2pack<<<64, 256, 0, stream>>>(W2, w2p);
    attn_kernel<<<8192, 256, 0, stream>>>(X, emb, wqt, wkt, wvt, wrt, Wlin, att_logit);
    dnn_kernel<<<512, 256, 0, stream>>>(X, emb, w1p, b1, w2p, b2, W3, b3, att_logit,
                                        (float*)d_out);
}